// Round 4
// baseline (167.785 us; speedup 1.0000x reference)
//
#include <hip/hip_runtime.h>
#include <math.h>

#define NN 50000
#define NE 800000
#define HD 128
#define ED 4
#define NL 4
#define MH 64
#define NE2 (NE / 2)        // 400000, MLP: 2 edges/thread
#define NBIN 782            // bin = dst >> 6 ; 49999>>6 = 781
#define NCAP 1536           // edges/bin: 1023 +- 32 (sd) -> 1536 is ~16 sigma
#define SCAP (NBIN * NCAP)  // sorted-array stride per layer
#define CURSTRIDE 16        // pad cursors to one per 64B line
#define NBF 782             // bin_fill blocks: (NE/4 + 255)/256
#define NMLPB 1563          // MLP blocks per layer: (NE2 + 255)/256

__device__ __forceinline__ float softplus_f(float a) {
    return fmaxf(a, 0.0f) + __logf(1.0f + __expf(-fabsf(a)));
}

// ---------------- fused: bin_fill (blocks 0..NBF-1) + edge MLP (rest) ----------
// DAG-independent stages share one dispatch. MLP is layer-parallel.
// Record int2 {src, (dloc<<20)|e}; dloc = dst&63 (6b), e < 2^20.
__global__ __launch_bounds__(256) void fused_bin_mlp_kernel(
    const int* __restrict__ eidx,
    int* __restrict__ gcur,          // NBIN*CURSTRIDE ints, pre-zeroed
    int2* __restrict__ gbin,         // NBIN*NCAP records
    const float* __restrict__ edge_attr,
    const float* __restrict__ ew1, const float* __restrict__ eb1,
    const float* __restrict__ ew2, const float* __restrict__ eb2,
    float* __restrict__ k_all)
{
    __shared__ int hist[NBIN];
    __shared__ int base[NBIN];

    if (blockIdx.x < NBF) {
        int tid = threadIdx.x;
        for (int i = tid; i < NBIN; i += 256) hist[i] = 0;
        __syncthreads();

        int e0 = (blockIdx.x * 256 + tid) * 4;
        int bin[4], dloc[4], rank[4];
        int4 srcs, dsts;
        bool act = e0 < NE;
        if (act) {
            srcs = *reinterpret_cast<const int4*>(eidx + e0);
            dsts = *reinterpret_cast<const int4*>(eidx + NE + e0);
            int dd[4] = {dsts.x, dsts.y, dsts.z, dsts.w};
            #pragma unroll
            for (int i = 0; i < 4; ++i) {
                bin[i]  = dd[i] >> 6;
                dloc[i] = dd[i] & 63;
                rank[i] = atomicAdd(&hist[bin[i]], 1);
            }
        }
        __syncthreads();
        for (int i = tid; i < NBIN; i += 256)
            if (hist[i]) base[i] = atomicAdd(&gcur[i * CURSTRIDE], hist[i]);
        __syncthreads();
        if (act) {
            int ss[4] = {srcs.x, srcs.y, srcs.z, srcs.w};
            #pragma unroll
            for (int i = 0; i < 4; ++i) {
                int pos = bin[i] * NCAP + base[bin[i]] + rank[i];
                gbin[pos] = make_int2(ss[i], (dloc[i] << 20) | (e0 + i));
            }
        }
        return;
    }

    // ---- edge MLP, one layer per block-group, 2 edges/thread ----
    int lb = blockIdx.x - NBF;
    int l  = lb / NMLPB;
    int t  = (lb - l * NMLPB) * 256 + threadIdx.x;
    if (t >= NE2) return;
    const int e0 = t, e1 = t + NE2;
    const float4 a0 = *reinterpret_cast<const float4*>(edge_attr + (size_t)e0 * 4);
    const float4 a1 = *reinterpret_cast<const float4*>(edge_attr + (size_t)e1 * 4);

    const float* __restrict__ W0 = ew1 + (size_t)(l * ED + 0) * MH;
    const float* __restrict__ W1 = ew1 + (size_t)(l * ED + 1) * MH;
    const float* __restrict__ W2 = ew1 + (size_t)(l * ED + 2) * MH;
    const float* __restrict__ W3 = ew1 + (size_t)(l * ED + 3) * MH;
    const float* __restrict__ B1 = eb1 + (size_t)l * MH;
    const float* __restrict__ V2 = ew2 + (size_t)l * MH;

    float acc0 = eb2[l], acc1 = acc0;
    #pragma unroll 8
    for (int j = 0; j < MH; ++j) {
        const float w0 = W0[j];
        const float w1 = W1[j];
        const float w2 = W2[j];
        const float w3 = W3[j];
        const float b1 = B1[j];
        const float v2 = V2[j];
        float m0 = fmaf(a0.x, w0, fmaf(a0.y, w1, fmaf(a0.z, w2, fmaf(a0.w, w3, b1))));
        float m1 = fmaf(a1.x, w0, fmaf(a1.y, w1, fmaf(a1.z, w2, fmaf(a1.w, w3, b1))));
        acc0 = fmaf(fmaxf(m0, 0.0f), v2, acc0);
        acc1 = fmaf(fmaxf(m1, 0.0f), v2, acc1);
    }
    k_all[(size_t)l * NE + e0] = softplus_f(acc0);
    k_all[(size_t)l * NE + e1] = softplus_f(acc1);
}

// ---------------- per-bin CSR build + k permute into sorted order --------------
// 782 blocks, 64 nodes/bin. Scatter also gathers the 4 per-layer k values
// (random L2 reads, paid ONCE) and writes them in CSR order so every
// downstream gather is a pure streaming read.
__global__ __launch_bounds__(256) void csr_kperm_kernel(
    const int* __restrict__ gcur,
    const int2* __restrict__ gbin,
    const float* __restrict__ k_all,
    int* __restrict__ gs_src,
    float* __restrict__ gs_k,        // [NL][SCAP]
    int2* __restrict__ nodeSD)       // {start, deg} per node
{
    __shared__ int cnt[64];
    __shared__ int cur[64];
    int b = blockIdx.x;
    int tid = threadIdx.x;
    int m = gcur[b * CURSTRIDE];
    const int2* src = gbin + (size_t)b * NCAP;

    if (tid < 64) cnt[tid] = 0;
    __syncthreads();
    for (int p = tid; p < m; p += 256) {
        int dloc = src[p].y >> 20;
        atomicAdd(&cnt[dloc], 1);
    }
    __syncthreads();
    if (tid < 64) {           // single-wave inclusive scan over 64 entries
        int v = cnt[tid];
        int x = v;
        #pragma unroll
        for (int o = 1; o < 64; o <<= 1) {
            int t = __shfl_up(x, o);
            if (tid >= o) x += t;
        }
        int excl = x - v;
        cur[tid] = excl;
        int n = (b << 6) + tid;
        if (n < NN) nodeSD[n] = make_int2(b * NCAP + excl, v);
    }
    __syncthreads();
    for (int p = tid; p < m; p += 256) {
        int2 r = src[p];
        int dloc = r.y >> 20;
        int e    = r.y & 0xFFFFF;
        float k0 = k_all[e];
        float k1 = k_all[(size_t)NE + e];
        float k2 = k_all[2 * (size_t)NE + e];
        float k3 = k_all[3 * (size_t)NE + e];
        int q = atomicAdd(&cur[dloc], 1);
        size_t o = (size_t)b * NCAP + q;
        gs_src[o] = r.x;
        gs_k[o]            = k0;
        gs_k[SCAP + o]     = k1;
        gs_k[2 * (size_t)SCAP + o] = k2;
        gs_k[3 * (size_t)SCAP + o] = k3;
    }
}

// ---------------- per-layer gather: fully streaming rows ----------------------
// s_out[n] = sum_p k_p*s_in[src_p] - (sum_p k_p)*s_in[n]; 16 lanes per node.
__global__ void sgather_kernel(const int2* __restrict__ nodeSD,
                               const int* __restrict__ gs_src,
                               const float* __restrict__ gs_kl,   // layer slice
                               const float* __restrict__ s_in,
                               float* __restrict__ s_out) {
    int t = blockIdx.x * 256 + threadIdx.x;
    int n = t >> 4;
    int gl = threadIdx.x & 15;
    if (n >= NN) return;
    int2 sd = nodeSD[n];
    float sk = 0.0f, sks = 0.0f;
    for (int p = gl; p < sd.y; p += 16) {
        int   s  = gs_src[sd.x + p];
        float kk = gs_kl[sd.x + p];
        sk += kk;
        sks = fmaf(kk, s_in[s], sks);
    }
    #pragma unroll
    for (int m = 1; m < 16; m <<= 1) {
        sk  += __shfl_xor(sk, m);
        sks += __shfl_xor(sks, m);
    }
    if (gl == 0) s_out[n] = fmaf(-sk, s_in[n], sks);
}

// ---------------- layer-3 gather fused with the output head ----------------
__global__ void sgather_head_kernel(const int2* __restrict__ nodeSD,
                                    const int* __restrict__ gs_src,
                                    const float* __restrict__ gs_k3,
                                    const float* __restrict__ s_in,
                                    const float* __restrict__ ew,
                                    const float* __restrict__ ow1,
                                    const float* __restrict__ b1,
                                    const float* __restrict__ w2,
                                    const float* __restrict__ b2,
                                    float* __restrict__ out) {
    __shared__ float su[HD], sb1[HD], sw2[HD];
    if (threadIdx.x < HD) {
        int j = threadIdx.x;
        float a = 0.0f;
        #pragma unroll 8
        for (int c = 0; c < HD; ++c) a = fmaf(ew[c], ow1[c * HD + j], a);
        su[j]  = a;
        sb1[j] = b1[j];
        sw2[j] = w2[j];
    }
    __syncthreads();

    int t = blockIdx.x * 256 + threadIdx.x;
    int n = t >> 4;
    int gl = threadIdx.x & 15;
    if (n >= NN) return;
    int2 sd = nodeSD[n];
    float sk = 0.0f, sks = 0.0f;
    for (int p = gl; p < sd.y; p += 16) {
        int   s  = gs_src[sd.x + p];
        float kk = gs_k3[sd.x + p];
        sk += kk;
        sks = fmaf(kk, s_in[s], sks);
    }
    #pragma unroll
    for (int m = 1; m < 16; m <<= 1) {
        sk  += __shfl_xor(sk, m);
        sks += __shfl_xor(sks, m);
    }
    float sv = fmaf(-sk, s_in[n], sks);   // all 16 lanes hold sv

    float acc = 0.0f;
    #pragma unroll
    for (int jj = 0; jj < 8; ++jj) {
        int j = gl + jj * 16;
        acc = fmaf(fmaxf(fmaf(sv, su[j], sb1[j]), 0.0f), sw2[j], acc);
    }
    #pragma unroll
    for (int m = 1; m < 16; m <<= 1) acc += __shfl_xor(acc, m);
    if (gl == 0) out[n] = acc + b2[0];
}

// ---------------- launch ----------------

extern "C" void kernel_launch(void* const* d_in, const int* in_sizes, int n_in,
                              void* d_out, int out_size, void* d_ws, size_t ws_size,
                              hipStream_t stream) {
    const float* x        = (const float*)d_in[0];
    const int*   eidx     = (const int*)d_in[1];
    const float* edge_attr= (const float*)d_in[2];
    const float* embed_w  = (const float*)d_in[3];
    // d_in[4] = embed_b (cancels in the message; unused)
    const float* ew1      = (const float*)d_in[5];
    const float* eb1      = (const float*)d_in[6];
    const float* ew2      = (const float*)d_in[7];
    const float* eb2      = (const float*)d_in[8];
    const float* ow1      = (const float*)d_in[9];
    const float* ob1      = (const float*)d_in[10];
    const float* ow2      = (const float*)d_in[11];
    const float* ob2      = (const float*)d_in[12];
    float* out = (float*)d_out;

    char* ws = (char*)d_ws;
    const size_t kbytes  = (size_t)NL * NE * sizeof(float);            // 12.8 MB
    const size_t gbbytes = (size_t)NBIN * NCAP * sizeof(int2);         // 9.6 MB
    const size_t srcbyte = (size_t)SCAP * sizeof(int);                 // 4.8 MB
    const size_t gskbyte = (size_t)NL * SCAP * sizeof(float);          // 19.2 MB
    const size_t curbyte = (size_t)NBIN * CURSTRIDE * sizeof(int);     // 50 KB
    const size_t sdbytes = (size_t)NN * sizeof(int2);                  // 400 KB
    const size_t sbytes  = (size_t)NN * sizeof(float);                 // 200 KB

    size_t off = 0;
    float* k_all   = (float*)(ws + off); off += kbytes;
    int2*  gbin    = (int2*) (ws + off); off += gbbytes;
    int*   gs_src  = (int*)  (ws + off); off += srcbyte;
    float* gs_k    = (float*)(ws + off); off += gskbyte;
    int*   gcur    = (int*)  (ws + off); off += curbyte;
    int2*  nodeSD  = (int2*) (ws + off); off += sdbytes;
    float* sA      = (float*)(ws + off); off += sbytes;
    float* sB      = (float*)(ws + off); off += sbytes;

    hipMemsetAsync(gcur, 0, curbyte, stream);

    fused_bin_mlp_kernel<<<NBF + NL * NMLPB, 256, 0, stream>>>(
        eidx, gcur, gbin, edge_attr, ew1, eb1, ew2, eb2, k_all);

    csr_kperm_kernel<<<NBIN, 256, 0, stream>>>(
        gcur, gbin, k_all, gs_src, gs_k, nodeSD);

    const int ggrid = (NN * 16 + 255) / 256;
    sgather_kernel<<<ggrid, 256, 0, stream>>>(nodeSD, gs_src, gs_k,            x,  sA);
    sgather_kernel<<<ggrid, 256, 0, stream>>>(nodeSD, gs_src, gs_k + SCAP,     sA, sB);
    sgather_kernel<<<ggrid, 256, 0, stream>>>(nodeSD, gs_src, gs_k + 2 * (size_t)SCAP, sB, sA);
    sgather_head_kernel<<<ggrid, 256, 0, stream>>>(nodeSD, gs_src, gs_k + 3 * (size_t)SCAP, sA,
                                                   embed_w, ow1, ob1, ow2, ob2, out);
}